// Round 12
// baseline (279.737 us; speedup 1.0000x reference)
//
#include <hip/hip_runtime.h>
#include <hip/hip_bf16.h>
#include <stdint.h>

typedef __bf16 bf16_t;
typedef __bf16 bf16x8 __attribute__((ext_vector_type(8)));
typedef float f32x4 __attribute__((ext_vector_type(4)));
typedef unsigned short u16;
typedef u16 u16x8 __attribute__((ext_vector_type(8)));
typedef u16 u16x4 __attribute__((ext_vector_type(4)));

#define AS1 __attribute__((address_space(1)))
#define AS3 __attribute__((address_space(3)))

__device__ __forceinline__ u16 f2bf(float f) {
    uint32_t u = __builtin_bit_cast(uint32_t, f);
    u += 0x7FFFu + ((u >> 16) & 1u);   // round-to-nearest-even
    return (u16)(u >> 16);
}
__device__ __forceinline__ float bf2f(u16 h) {
    return __builtin_bit_cast(float, (uint32_t)h << 16);
}
__device__ __forceinline__ u16 f2bf_fast(float f) {   // native cvt (RTE), 1 VALU op
    return __builtin_bit_cast(u16, (__bf16)f);
}

// ---------------------------------------------------------------- converts
__global__ void k_f32_to_bf16(const float* __restrict__ in, u16* __restrict__ out, int n4) {
    int i = blockIdx.x * blockDim.x + threadIdx.x;
    int stride = gridDim.x * blockDim.x;
    for (; i < n4; i += stride) {
        float4 v = ((const float4*)in)[i];
        ushort4 o;
        o.x = f2bf(v.x); o.y = f2bf(v.y); o.z = f2bf(v.z); o.w = f2bf(v.w);
        ((ushort4*)out)[i] = o;
    }
}

// ---------------------------------------------------------------- GEMM (C = A * B^T), A:MxK bf16, B:NxK bf16
// R12: 3-slot LDS pipeline with counted vmcnt + raw s_barrier (T3/T4 mechanism).
// BM=128 x BN=256 x BK=64, 512 thr (8 waves 2Mx4N, 64x64/wave), LDS 144KB.
// Ledger: iter i stages K-tile t+2 (6 gload_lds) into the slot freed at iter i-1's
// barrier (no WAR race); end-of-iter s_waitcnt vmcnt(6) retires exactly t+1's loads
// (oldest-first, per-wave-uniform counts); s_barrier publishes cross-wave; loads
// stay in flight across barriers (never drains to 0 in steady state). Last iters
// use vmcnt(0) (no new issues -> counted wait would under-wait).
// Both-sides chunk-XOR swizzle (chunk ^= row&7): 2-way LDS reads (free).
// OUTMODE 1: f32 MxN into C
// OUTMODE 3: cols<2048 -> bf16 C stride 2048 (Q); cols>=2048 -> bf16 C2 stride 512 (c_kv)
// OUTMODE 4: cols<2048 -> bf16 C stride 2048 (K); cols>=2048 -> V^T (b,h,d,s) into C2
template <int OUTMODE>
__global__ __launch_bounds__(512, 2) void k_gemm_bt(
    const u16* __restrict__ A, const u16* __restrict__ Bm,
    void* __restrict__ C, void* __restrict__ C2, int M, int N, int K)
{
    __shared__ __align__(16) u16 sA[3 * 128 * 64];
    __shared__ __align__(16) u16 sB[3 * 256 * 64];

    const int t = threadIdx.x;
    const int lane = t & 63;
    const int w = t >> 6;
    const int wr = w >> 2;        // M 64-row half (0..1)
    const int wc = w & 3;         // N 64-col quarter (0..3)

    // T1: bijective XCD-chunked swizzle (all our grids have nwg % 8 == 0)
    const int nwg = gridDim.x * gridDim.y;
    const int id = blockIdx.y * gridDim.x + blockIdx.x;
    const int id2 = (id & 7) * (nwg >> 3) + (id >> 3);
    const int bx = id2 % gridDim.x, by = id2 / gridDim.x;
    const int bm = by * 128, bn = bx * 256;

    // staging: chunkid = issue*512 + t; row = chunkid>>3, lds chunk = chunkid&7.
    // pre-swizzled SOURCE chunk = (t&7) ^ ((t>>3)&7)  (issue*64 ≡ 0 mod 8 -> constant)
    const int srow = t >> 3;
    const int scol = ((t & 7) ^ (srow & 7)) * 8;
    const size_t aBase = (size_t)(bm + srow) * K + scol;
    const size_t bBase = (size_t)(bn + srow) * K + scol;

    const int fr = lane & 15;
    const int g4 = lane >> 4;

    f32x4 acc[4][4];
    const f32x4 fzero = {0.f, 0.f, 0.f, 0.f};
#pragma unroll
    for (int i = 0; i < 4; ++i)
#pragma unroll
        for (int j = 0; j < 4; ++j) acc[i][j] = fzero;

    auto stage = [&](int sl, int k0) {
        char* da = (char*)(sA + sl * (128 * 64));
        char* db = (char*)(sB + sl * (256 * 64));
#pragma unroll
        for (int i = 0; i < 2; ++i)
            __builtin_amdgcn_global_load_lds(
                (const AS1 void*)(A + aBase + (size_t)(i * 64) * K + k0),
                (AS3 void*)(da + i * 8192 + t * 16), 16, 0, 0);
#pragma unroll
        for (int i = 0; i < 4; ++i)
            __builtin_amdgcn_global_load_lds(
                (const AS1 void*)(Bm + bBase + (size_t)(i * 64) * K + k0),
                (AS3 void*)(db + i * 8192 + t * 16), 16, 0, 0);
    };

    auto compute = [&](int sl) {
        const char* sa = (const char*)(sA + sl * (128 * 64));
        const char* sb = (const char*)(sB + sl * (256 * 64));
        bf16x8 af[4][2], bfv[4][2];
#pragma unroll
        for (int mi = 0; mi < 4; ++mi) {
            const int row = wr * 64 + mi * 16 + fr;
#pragma unroll
            for (int kk = 0; kk < 2; ++kk)
                af[mi][kk] = *(const bf16x8*)(sa + row * 128 + (((kk * 4 + g4) ^ (row & 7)) << 4));
        }
#pragma unroll
        for (int ni = 0; ni < 4; ++ni) {
            const int row = wc * 64 + ni * 16 + fr;
#pragma unroll
            for (int kk = 0; kk < 2; ++kk)
                bfv[ni][kk] = *(const bf16x8*)(sb + row * 128 + (((kk * 4 + g4) ^ (row & 7)) << 4));
        }
#pragma unroll
        for (int kk = 0; kk < 2; ++kk)
#pragma unroll
            for (int mi = 0; mi < 4; ++mi)
#pragma unroll
                for (int ni = 0; ni < 4; ++ni)
                    acc[mi][ni] = __builtin_amdgcn_mfma_f32_16x16x32_bf16(
                        af[mi][kk], bfv[ni][kk], acc[mi][ni], 0, 0, 0);
    };

    // ---- 3-slot pipelined K loop (nK >= 3 for all our shapes: 32, 8, 32)
    const int nK = K >> 6;
    stage(0, 0);
    stage(1, 64);
    asm volatile("s_waitcnt vmcnt(6)" ::: "memory");   // retire K-tile 0's 6 loads
    __builtin_amdgcn_s_barrier();
    __builtin_amdgcn_sched_barrier(0);
    for (int ti = 0; ti < nK; ++ti) {
        const bool more = (ti + 2 < nK);
        if (more) stage((ti + 2) % 3, (ti + 2) * 64);
        compute(ti % 3);
        if (more) asm volatile("s_waitcnt vmcnt(6)" ::: "memory");  // retire t+1's loads
        else      asm volatile("s_waitcnt vmcnt(0)" ::: "memory");  // tail drain
        __builtin_amdgcn_s_barrier();
        __builtin_amdgcn_sched_barrier(0);
    }

    const int cr = g4 * 4;
    const int cc = fr;
#pragma unroll
    for (int mi = 0; mi < 4; ++mi) {
#pragma unroll
        for (int ni = 0; ni < 4; ++ni) {
            const int row = bm + wr * 64 + mi * 16 + cr;
            const int col = bn + wc * 64 + ni * 16 + cc;
            if constexpr (OUTMODE == 1) {
#pragma unroll
                for (int r = 0; r < 4; ++r)
                    ((float*)C)[(size_t)(row + r) * N + col] = acc[mi][ni][r];
            } else if constexpr (OUTMODE == 3) {
                if (col < 2048) {
#pragma unroll
                    for (int r = 0; r < 4; ++r)
                        ((u16*)C)[(size_t)(row + r) * 2048 + col] = f2bf(acc[mi][ni][r]);
                } else {
#pragma unroll
                    for (int r = 0; r < 4; ++r)
                        ((u16*)C2)[(size_t)(row + r) * 512 + (col - 2048)] = f2bf(acc[mi][ni][r]);
                }
            } else if constexpr (OUTMODE == 4) {
                if (col < 2048) {
#pragma unroll
                    for (int r = 0; r < 4; ++r)
                        ((u16*)C)[(size_t)(row + r) * 2048 + col] = f2bf(acc[mi][ni][r]);
                } else {
                    const int c2 = col - 2048;
                    const int b = row >> 11, s0 = row & 2047;
                    const int h = c2 >> 7, d = c2 & 127;
                    u16x4 pk;
#pragma unroll
                    for (int r = 0; r < 4; ++r) pk[r] = f2bf(acc[mi][ni][r]);
                    *(u16x4*)((u16*)C2 + ((size_t)((b * 16 + h) * 128 + d)) * 2048 + s0) = pk;
                }
            }
        }
    }
}

// ---------------------------------------------------------------- RoPE in place on (B*S, H*128) bf16
__global__ void k_rope(u16* __restrict__ x, int S, int n) {
    int i = blockIdx.x * blockDim.x + threadIdx.x;
    if (i >= n) return;
    const int j = i & 63;
    const int h = (i >> 6) & 15;
    const int row = i >> 10;
    const int s = row & (S - 1);
    const float L2B = 13.287712379549449f;
    float inv = exp2f(-(float)(2 * j) * (L2B / 128.f));
    float ang = (float)s * inv;
    float c, sn;
    sincosf(ang, &sn, &c);
    size_t base = (size_t)row * 2048 + h * 128 + j;
    float x1 = bf2f(x[base]);
    float x2 = bf2f(x[base + 64]);
    x[base]      = f2bf(x1 * c - x2 * sn);
    x[base + 64] = f2bf(x2 * c + x1 * sn);
}

// ---------------------------------------------------------------- MFMA flash attention (causal)
// R10/R11 (proven ~69us): 512-thread blocks, 8 waves = 4 rowgroups x 2 KV parities,
// 2-phase static-dbuf staging, heavy-first XCD-chunked dispatch, fixed-shift softmax
// P = exp2(s-8) (exact; shift cancels), both-sides swizzles, simplified parity merge.
__global__ __launch_bounds__(512, 2) void k_flash_mfma(
    const u16* __restrict__ Q, const u16* __restrict__ K, const u16* __restrict__ VT,
    u16* __restrict__ O)
{
    constexpr int S = 2048, HD = 2048;
    constexpr float M0 = 8.f;                     // fixed log2-domain shift
    __shared__ __align__(16) u16 K0A[32 * 128];
    __shared__ __align__(16) u16 K1A[32 * 128];
    __shared__ __align__(16) u16 K0B[32 * 128];
    __shared__ __align__(16) u16 K1B[32 * 128];
    __shared__ __align__(16) u16 V0A[128 * 32];
    __shared__ __align__(16) u16 V1A[128 * 32];
    __shared__ __align__(16) u16 V0B[128 * 32];
    __shared__ __align__(16) u16 V1B[128 * 32];
    __shared__ __align__(16) u16 Pl[8][32 * 40];
    __shared__ __align__(16) u16 MO[4][32][128];  // parity-1 partial O (bf16)
    __shared__ float ML[4][32];                   // parity-1 partial l

    const int t = threadIdx.x;
    const int lane = t & 63;
    const int w = t >> 6;
    const int rg = w >> 1;        // row group 0..3
    const int h = w & 1;          // KV tile parity

    const int bid = blockIdx.x;                   // 512 blocks
    const int lg = (bid & 7) * 64 + (bid >> 3);
    const int c  = lg & 63;
    const int pair = (lg >> 6) * 4 + (c & 3);     // (b,h) 0..31
    const int qt = 15 - (c >> 2);                 // heavy-first
    const int b = pair >> 4, hh = pair & 15;
    const int wq0 = qt * 128 + rg * 32;

    const u16* qg = Q + ((size_t)b * S) * HD + hh * 128;
    const u16* kg = K + ((size_t)b * S) * HD + hh * 128;
    const u16* vg = VT + ((size_t)pair) * 128 * S;

    const int r16 = lane & 15;
    const int g4 = lane >> 4;

    // Q fragments, pre-scaled by (1/sqrt(128)) * log2(e)  -> log2-domain scores
    const float scale = 0.08838834764831845f * 1.4426950408889634f;
    bf16x8 aQ[2][4];
#pragma unroll
    for (int qi = 0; qi < 2; ++qi) {
        const u16* qr = qg + (size_t)(wq0 + qi * 16 + r16) * HD;
#pragma unroll
        for (int dk = 0; dk < 4; ++dk) {
            u16x8 u = *(const u16x8*)(qr + dk * 32 + g4 * 8);
            u16x8 uu;
#pragma unroll
            for (int j = 0; j < 8; ++j) uu[j] = f2bf(bf2f(u[j]) * scale);
            aQ[qi][dk] = __builtin_bit_cast(bf16x8, uu);
        }
    }

    f32x4 oa[2][8];
    f32x4 lP[2];
    const f32x4 fzero = {0.f, 0.f, 0.f, 0.f};
#pragma unroll
    for (int qi = 0; qi < 2; ++qi) {
        lP[qi] = fzero;
#pragma unroll
        for (int dj = 0; dj < 8; ++dj) oa[qi][dj] = fzero;
    }

    const int diag = 4 * qt + rg;
    const int tend = ((diag & 1) == h) ? diag : diag - 1;   // may be -1
    const int nr = 2 * qt + 2;

    // stage one ROUND (tiles j0/32, j0/32+1): K pair + V pair, 512 thr x 16B each
    auto stage = [&](u16 (&Kd0)[32 * 128], u16 (&Kd1)[32 * 128],
                     u16 (&Vd0)[128 * 32], u16 (&Vd1)[128 * 32], int j0) {
        const int off = t * 16;
        const int kv = off >> 8, c16 = (off >> 4) & 15;   // K rows 256B, 16 chunks
        const int ck = (c16 ^ (kv & 15)) * 8;
        __builtin_amdgcn_global_load_lds(
            (const AS1 void*)(kg + (size_t)(j0 + kv) * HD + ck),
            (AS3 void*)((char*)&Kd0[0] + off), 16, 0, 0);
        __builtin_amdgcn_global_load_lds(
            (const AS1 void*)(kg + (size_t)(j0 + 32 + kv) * HD + ck),
            (AS3 void*)((char*)&Kd1[0] + off), 16, 0, 0);
        const int d = off >> 6, cv = (off >> 4) & 3;      // V rows 64B, 4 chunks
        const int cx = (cv ^ ((d >> 1) & 3)) * 8;         // spread over 8 bank-groups
        __builtin_amdgcn_global_load_lds(
            (const AS1 void*)(vg + (size_t)d * S + j0 + cx),
            (AS3 void*)((char*)&Vd0[0] + off), 16, 0, 0);
        __builtin_amdgcn_global_load_lds(
            (const AS1 void*)(vg + (size_t)d * S + j0 + 32 + cx),
            (AS3 void*)((char*)&Vd1[0] + off), 16, 0, 0);
    };

    auto compute = [&](int tix, const u16* Kc, const u16* Vc) {
        // ---- QK^T : 32q x 32kv
        f32x4 sc[2][2];
#pragma unroll
        for (int qi = 0; qi < 2; ++qi) { sc[qi][0] = fzero; sc[qi][1] = fzero; }
#pragma unroll
        for (int dk = 0; dk < 4; ++dk) {
            const int kv0 = r16, kv1 = 16 + r16;
            bf16x8 k0 = *(const bf16x8*)((const char*)Kc +
                         kv0 * 256 + (((dk * 4 + g4) ^ (kv0 & 15)) << 4));
            bf16x8 k1 = *(const bf16x8*)((const char*)Kc +
                         kv1 * 256 + (((dk * 4 + g4) ^ (kv1 & 15)) << 4));
            sc[0][0] = __builtin_amdgcn_mfma_f32_16x16x32_bf16(aQ[0][dk], k0, sc[0][0], 0, 0, 0);
            sc[0][1] = __builtin_amdgcn_mfma_f32_16x16x32_bf16(aQ[0][dk], k1, sc[0][1], 0, 0, 0);
            sc[1][0] = __builtin_amdgcn_mfma_f32_16x16x32_bf16(aQ[1][dk], k0, sc[1][0], 0, 0, 0);
            sc[1][1] = __builtin_amdgcn_mfma_f32_16x16x32_bf16(aQ[1][dk], k1, sc[1][1], 0, 0, 0);
        }

        // ---- causal mask on the diagonal tile (C layout: row=g4*4+r, col=r16)
        if (tix == diag) {
#pragma unroll
            for (int qi = 0; qi < 2; ++qi)
#pragma unroll
                for (int kf = 0; kf < 2; ++kf)
#pragma unroll
                    for (int r = 0; r < 4; ++r) {
                        const int lr = qi * 16 + g4 * 4 + r;
                        const int lc = kf * 16 + r16;
                        if (lc > lr) sc[qi][kf][r] = -1e30f;
                    }
        }

        // ---- fixed-shift softmax: P = exp2(s - M0); no reductions, no rescale
#pragma unroll
        for (int qi = 0; qi < 2; ++qi)
#pragma unroll
            for (int kf = 0; kf < 2; ++kf)
#pragma unroll
                for (int r = 0; r < 4; ++r) {
                    float pp = __builtin_amdgcn_exp2f(sc[qi][kf][r] - M0);
                    lP[qi][r] += pp;
                    Pl[w][(qi * 16 + g4 * 4 + r) * 40 + kf * 16 + r16] = f2bf_fast(pp);
                }

        // ---- PV : O += P @ V
        bf16x8 pa[2];
#pragma unroll
        for (int qi = 0; qi < 2; ++qi)
            pa[qi] = *(const bf16x8*)&Pl[w][(qi * 16 + r16) * 40 + g4 * 8];
#pragma unroll
        for (int dj = 0; dj < 8; ++dj) {
            const int d = dj * 16 + r16;
            bf16x8 bV = *(const bf16x8*)((const char*)Vc +
                         d * 64 + ((g4 ^ ((d >> 1) & 3)) << 4));
            oa[0][dj] = __builtin_amdgcn_mfma_f32_16x16x32_bf16(pa[0], bV, oa[0][dj], 0, 0, 0);
            oa[1][dj] = __builtin_amdgcn_mfma_f32_16x16x32_bf16(pa[1], bV, oa[1][dj], 0, 0, 0);
        }
    };

    const u16* myKA = h ? &K1A[0] : &K0A[0];
    const u16* myVA = h ? &V1A[0] : &V0A[0];
    const u16* myKB = h ? &K1B[0] : &K0B[0];
    const u16* myVB = h ? &V1B[0] : &V0B[0];

    // ---- 2-phase pipelined main loop over rounds (nr is even)
    stage(K0A, K1A, V0A, V1A, 0);
    __syncthreads();
    for (int j = 0; j < nr; j += 2) {
        if (j + 1 < nr) stage(K0B, K1B, V0B, V1B, (j + 1) * 64);
        { const int tix = 2 * j + h; if (tix <= tend) compute(tix, myKA, myVA); }
        __syncthreads();
        if (j + 2 < nr) stage(K0A, K1A, V0A, V1A, (j + 2) * 64);
        { const int tix = 2 * (j + 1) + h; if (tix <= tend) compute(tix, myKB, myVB); }
        __syncthreads();
    }

    // ---- reduce per-lane partial l across the 16-lane row group
#pragma unroll
    for (int qi = 0; qi < 2; ++qi)
#pragma unroll
        for (int r = 0; r < 4; ++r) {
            float v = lP[qi][r];
            v += __shfl_xor(v, 1);
            v += __shfl_xor(v, 2);
            v += __shfl_xor(v, 4);
            v += __shfl_xor(v, 8);
            lP[qi][r] = v;
        }

    // ---- merge parity halves: shared fixed max -> O = (o0+o1)/(l0+l1)
    if (h) {
#pragma unroll
        for (int qi = 0; qi < 2; ++qi)
#pragma unroll
            for (int r = 0; r < 4; ++r) {
                const int row = qi * 16 + g4 * 4 + r;
                ML[rg][row] = lP[qi][r];
#pragma unroll
                for (int dj = 0; dj < 8; ++dj)
                    MO[rg][row][dj * 16 + r16] = f2bf_fast(oa[qi][dj][r]);
            }
    }
    __syncthreads();
    if (!h) {
#pragma unroll
        for (int qi = 0; qi < 2; ++qi) {
#pragma unroll
            for (int r = 0; r < 4; ++r) {
                const int row = qi * 16 + g4 * 4 + r;
                const float inv = 1.f / (lP[qi][r] + ML[rg][row]);
                u16* orow = O + (size_t)(b * S + wq0 + row) * HD + hh * 128;
#pragma unroll
                for (int dj = 0; dj < 8; ++dj) {
                    const float o2 = bf2f(MO[rg][row][dj * 16 + r16]);
                    orow[dj * 16 + r16] = f2bf((oa[qi][dj][r] + o2) * inv);
                }
            }
        }
    }
}

// ---------------------------------------------------------------- launch
extern "C" void kernel_launch(void* const* d_in, const int* in_sizes, int n_in,
                              void* d_out, int out_size, void* d_ws, size_t ws_size,
                              hipStream_t stream) {
    const float* hs = (const float*)d_in[0];
    const float* Wq = (const float*)d_in[1];
    const float* Wc = (const float*)d_in[2];
    const float* Wk = (const float*)d_in[3];
    const float* Wv = (const float*)d_in[4];
    const float* Wo = (const float*)d_in[5];

    const int B = 2, S = 2048, D = 2048, DL = 512, H = 16;
    const int M = B * S;   // 4096

    char* p = (char*)d_ws;
    u16* hs_bf   = (u16*)p; p += (size_t)M * D * 2;
    u16* WqWc_bf = (u16*)p; p += (size_t)(D + DL) * D * 2;     // Wq rows 0..2047, Wc rows 2048..2559
    u16* WkWv_bf = (u16*)p; p += (size_t)(2 * D) * DL * 2;     // Wk rows 0..2047, Wv rows 2048..4095
    u16* Wo_bf   = (u16*)p; p += (size_t)D * D * 2;
    u16* qb      = (u16*)p; p += (size_t)M * D * 2;
    u16* kb      = (u16*)p; p += (size_t)M * D * 2;
    u16* vbT     = (u16*)p; p += (size_t)M * D * 2;            // (B,H,128,S)
    u16* ckv     = (u16*)p; p += (size_t)M * DL * 2;
    u16* attn    = (u16*)p; p += (size_t)M * D * 2;

    auto conv = [&](const float* in, u16* out, size_t n) {
        int n4 = (int)(n / 4);
        int blocks = (n4 + 255) / 256;
        if (blocks > 4096) blocks = 4096;
        k_f32_to_bf16<<<blocks, 256, 0, stream>>>(in, out, n4);
    };
    conv(hs, hs_bf, (size_t)M * D);
    conv(Wq, WqWc_bf, (size_t)D * D);
    conv(Wc, WqWc_bf + (size_t)D * D, (size_t)DL * D);
    conv(Wk, WkWv_bf, (size_t)D * DL);
    conv(Wv, WkWv_bf + (size_t)D * DL, (size_t)D * DL);
    conv(Wo, Wo_bf, (size_t)D * D);

    // fused: [q | c_kv] = hs @ [Wq;Wc]^T   (N = 2560, 10x32 blocks)
    k_gemm_bt<3><<<dim3((D + DL) / 256, M / 128), 512, 0, stream>>>(
        hs_bf, WqWc_bf, qb, ckv, M, D + DL, D);
    // fused: [k | v] = c_kv @ [Wk;Wv]^T    (N = 4096, 16x32), v written as V^T (b,h,d,s)
    k_gemm_bt<4><<<dim3((2 * D) / 256, M / 128), 512, 0, stream>>>(
        ckv, WkWv_bf, kb, vbT, M, 2 * D, DL);

    {
        int n = M * H * 64;
        int blocks = (n + 255) / 256;
        k_rope<<<blocks, 256, 0, stream>>>(qb, S, n);
        k_rope<<<blocks, 256, 0, stream>>>(kb, S, n);
    }

    k_flash_mfma<<<512, 512, 0, stream>>>(qb, kb, vbT, attn);

    // out = attn @ Wo^T  (fp32 out, 8x32 blocks)
    k_gemm_bt<1><<<dim3(D / 256, M / 128), 512, 0, stream>>>(
        attn, Wo_bf, (float*)d_out, nullptr, M, D, D);
}